// Round 6
// baseline (731.001 us; speedup 1.0000x reference)
//
#include <hip/hip_runtime.h>
#include <hip/hip_bf16.h>

#define NN 50000
#define EE 640000
#define LN_EPS 1e-5f
#define KD 272              // extended K (256 feat + deg + md + 1 + 13 zero pad)
#define KB 544              // bytes per feat/W1 row (KD*2)
#define NBK 391             // buckets of 128 nodes (src >> 7)
#define CH 4096             // edges per binning block

typedef __bf16 bf16x8 __attribute__((ext_vector_type(8)));
typedef float f32x16 __attribute__((ext_vector_type(16)));

static __device__ __forceinline__ unsigned short f2bf(float f) {
    return __builtin_bit_cast(unsigned short, (__bf16)f);
}
static __device__ __forceinline__ float bflo(unsigned int u) {   // low bf16 of dword
    return __builtin_bit_cast(float, u << 16);
}
static __device__ __forceinline__ float bfhi(unsigned int u) {   // high bf16 of dword
    return __builtin_bit_cast(float, u & 0xffff0000u);
}

// ---- cast x to bf16 (gather source)
__global__ __launch_bounds__(256) void cast_x(const float* __restrict__ x,
                                              unsigned short* __restrict__ xbf) {
    int i = blockIdx.x * 256 + threadIdx.x;          // 8 elems per thread, 3125 blocks exact
    const float4* s = (const float4*)x + (size_t)i * 2;
    float4 a = s[0], b = s[1];
    unsigned short o[8] = { f2bf(a.x), f2bf(a.y), f2bf(a.z), f2bf(a.w),
                            f2bf(b.x), f2bf(b.y), f2bf(b.z), f2bf(b.w) };
    *(uint4*)(xbf + (size_t)i * 8) = *(const uint4*)o;
}

// ---- weight prep: W1Te[c][k] (512 x 272): k<256 = W1[k][c]; 256=W1[256][c]; 257=W1[257][c];
//      258=b1[c]; 259..271=0.  W2T[c][k] (128 x 512) = W2[k][c].
__global__ __launch_bounds__(256) void prep_weights(const float* __restrict__ W1,
                                                    const float* __restrict__ b1,
                                                    const float* __restrict__ W2,
                                                    unsigned short* __restrict__ W1Te,
                                                    unsigned short* __restrict__ W2T) {
    int b = blockIdx.x, tid = threadIdx.x;
    if (b < 512) {
        W1Te[(size_t)b * KD + tid] = f2bf(W1[(size_t)tid * 512 + b]);
        if (tid < 16) {
            float v = 0.f;
            if (tid == 0) v = W1[256 * 512 + b];
            else if (tid == 1) v = W1[257 * 512 + b];
            else if (tid == 2) v = b1[b];
            W1Te[(size_t)b * KD + 256 + tid] = f2bf(v);
        }
    } else {
        int c = b - 512;
        W2T[(size_t)c * 512 + tid]       = f2bf(W2[(size_t)tid * 128 + c]);
        W2T[(size_t)c * 512 + 256 + tid] = f2bf(W2[(size_t)(256 + tid) * 128 + c]);
    }
}

// ---- per-bucket edge counts from degrees (exact: degrees are src out-degrees)
__global__ __launch_bounds__(128) void hist_kernel(const float* __restrict__ degrees,
                                                   int* __restrict__ bcnt) {
    __shared__ int ws[2];
    int tid = threadIdx.x, lane = tid & 63, wid = tid >> 6;
    int i = blockIdx.x * 128 + tid;
    int v = (i < NN) ? (int)(degrees[i] + 0.5f) : 0;
    int s = v;
    for (int d = 1; d < 64; d <<= 1) s += __shfl_xor(s, d, 64);
    if (lane == 0) ws[wid] = s;
    __syncthreads();
    if (tid == 0) bcnt[blockIdx.x] = ws[0] + ws[1];
}

// ---- exclusive scan of 391 bucket counts -> gbase; init gcur
__global__ __launch_bounds__(256) void scan_buckets(const int* __restrict__ bcnt,
                                                    int* __restrict__ gbase,
                                                    int* __restrict__ gcur) {
    __shared__ int wsum[4];
    int tid = threadIdx.x, lane = tid & 63, wid = tid >> 6;
    int t2 = tid * 2;
    int v0 = (t2 < NBK) ? bcnt[t2] : 0;
    int v1 = (t2 + 1 < NBK) ? bcnt[t2 + 1] : 0;
    int s2 = v0 + v1;
    int inc = s2;
    for (int d = 1; d < 64; d <<= 1) { int t = __shfl_up(inc, d, 64); if (lane >= d) inc += t; }
    if (lane == 63) wsum[wid] = inc;
    __syncthreads();
    int base = 0;
    for (int w = 0; w < wid; w++) base += wsum[w];
    int ep = base + inc - s2;
    if (t2 < NBK)     { gbase[t2] = ep;      gcur[t2] = ep; }
    if (t2 + 1 < NBK) { gbase[t2 + 1] = ep + v0; gcur[t2 + 1] = ep + v0; }
}

// ---- bin edges into bucket-major record array with LDS staging (coalesced writeout)
// record = {dst:u32, (src&127)<<16 | bf16(dist)}
__global__ __launch_bounds__(256) void bin_kernel(const int* __restrict__ ei,
                                                  const float* __restrict__ edist,
                                                  int* __restrict__ gcur,
                                                  uint2* __restrict__ recs) {
    __shared__ int cnt[NBK], off[NBK], gb[NBK], c2[NBK];
    __shared__ int wsum[4];
    __shared__ uint2 stage[CH];
    __shared__ int gtg[CH];
    int tid = threadIdx.x, lane = tid & 63, wid = tid >> 6;
    int e0 = blockIdx.x * CH;
    int nval = EE - e0; if (nval > CH) nval = CH;

    for (int i = tid; i < NBK; i += 256) { cnt[i] = 0; c2[i] = 0; }
    __syncthreads();
#pragma unroll
    for (int k = 0; k < CH / 256; k++) {
        int e = e0 + k * 256 + tid;
        if (e < EE) atomicAdd(&cnt[ei[e] >> 7], 1);
    }
    __syncthreads();
    // exclusive scan of cnt -> off (256 threads x 2 elems)
    {
        int t2 = tid * 2;
        int v0 = (t2 < NBK) ? cnt[t2] : 0;
        int v1 = (t2 + 1 < NBK) ? cnt[t2 + 1] : 0;
        int s2 = v0 + v1;
        int inc = s2;
        for (int d = 1; d < 64; d <<= 1) { int t = __shfl_up(inc, d, 64); if (lane >= d) inc += t; }
        if (lane == 63) wsum[wid] = inc;
        __syncthreads();
        int base = 0;
        for (int w = 0; w < wid; w++) base += wsum[w];
        int ep = base + inc - s2;
        if (t2 < NBK)     off[t2] = ep;
        if (t2 + 1 < NBK) off[t2 + 1] = ep + v0;
    }
    __syncthreads();
    // reserve global ranges
    for (int i = tid; i < NBK; i += 256) {
        int c = cnt[i];
        gb[i] = c ? atomicAdd(&gcur[i], c) : 0;
    }
    __syncthreads();
    // stage records bucket-major
#pragma unroll
    for (int k = 0; k < CH / 256; k++) {
        int e = e0 + k * 256 + tid;
        if (e < EE) {
            int s = ei[e];
            int d = ei[EE + e];
            float dv = edist[e];
            int b = s >> 7;
            int p = atomicAdd(&c2[b], 1);
            int slot = off[b] + p;
            stage[slot] = make_uint2((unsigned)d, ((unsigned)(s & 127) << 16) | f2bf(dv));
            gtg[slot] = gb[b] + p;
        }
    }
    __syncthreads();
    // coalesced-run writeout
    for (int i = tid; i < nval; i += 256)
        recs[gtg[i]] = stage[i];
}

// ---- per-half-bucket LDS aggregation + feat emit.
// block = 64 nodes (bucket>>1, half). agg LDS column-PERMUTED: [r][l]=col 2l, [r][64+l]=col 2l+1
// (2-way bank aliasing = free, vs 4-way natural).
__global__ __launch_bounds__(256) void aggbucket_kernel(const unsigned short* __restrict__ xbf,
                                                        const uint2* __restrict__ recs,
                                                        const int* __restrict__ gbase,
                                                        const int* __restrict__ bcnt,
                                                        const float* __restrict__ degrees,
                                                        unsigned short* __restrict__ featbf) {
    __shared__ float agg[64][128];   // 32KB
    __shared__ float dl[64];
    int tid = threadIdx.x, wave = tid >> 6, lane = tid & 63;
    int bkt = blockIdx.x >> 1, half = blockIdx.x & 1;
    int st = gbase[bkt], cnt = bcnt[bkt];

    for (int k = tid; k < 64 * 128; k += 256) ((float*)agg)[k] = 0.f;
    if (tid < 64) dl[tid] = 0.f;
    __syncthreads();

    for (int i = wave * 2; i < cnt; i += 8) {
        uint2 rA = recs[st + i];
        bool hasB = (i + 1) < cnt;
        uint2 rB = hasB ? recs[st + i + 1] : make_uint2(0u, 0u);
        unsigned sA = rA.y >> 16, sB = rB.y >> 16;
        bool doA = (sA >> 6) == (unsigned)half;
        bool doB = hasB && ((sB >> 6) == (unsigned)half);
        unsigned xvA = 0, xvB = 0;
        if (doA) xvA = *(const unsigned*)(xbf + (size_t)rA.x * 128 + lane * 2);
        if (doB) xvB = *(const unsigned*)(xbf + (size_t)rB.x * 128 + lane * 2);
        if (doA) {
            int r = sA & 63;
            atomicAdd(&agg[r][lane], bflo(xvA));
            atomicAdd(&agg[r][64 + lane], bfhi(xvA));
            if (lane == 0) atomicAdd(&dl[r], bflo(rA.y));
        }
        if (doB) {
            int r = sB & 63;
            atomicAdd(&agg[r][lane], bflo(xvB));
            atomicAdd(&agg[r][64 + lane], bfhi(xvB));
            if (lane == 0) atomicAdd(&dl[r], bflo(rB.y));
        }
    }
    __syncthreads();

    // emit: 64 rows x 4 segs of 32 cols
    int r = tid >> 2, seg = tid & 3;
    int node = bkt * 128 + half * 64 + r;
    if (node >= NN) return;
    float dg = degrees[node];
    float degc = fmaxf(dg, 1.0f);
    float inv = 1.0f / degc;
    unsigned short* row = featbf + (size_t)node * KD;
    // self feature copy: full 32 columns (4 x uint4 = 4 x 8 bf16)
    const unsigned short* xr = xbf + (size_t)node * 128 + seg * 32;
    uint4 sa = *(const uint4*)(xr);
    uint4 sb = *(const uint4*)(xr + 8);
    uint4 sc = *(const uint4*)(xr + 16);
    uint4 sd = *(const uint4*)(xr + 24);
    *(uint4*)(row + seg * 32)      = sa;
    *(uint4*)(row + seg * 32 + 8)  = sb;
    *(uint4*)(row + seg * 32 + 16) = sc;
    *(uint4*)(row + seg * 32 + 24) = sd;
    // aggregated feature (un-permute)
    unsigned short o[32];
#pragma unroll
    for (int k = 0; k < 32; k++) {
        int c = seg * 32 + k;
        float v = agg[r][((c & 1) << 6) + (c >> 1)] * inv;
        o[k] = f2bf(v);
    }
    *(uint4*)(row + 128 + seg * 32)      = *(const uint4*)(o);
    *(uint4*)(row + 128 + seg * 32 + 8)  = *(const uint4*)(o + 8);
    *(uint4*)(row + 128 + seg * 32 + 16) = *(const uint4*)(o + 16);
    *(uint4*)(row + 128 + seg * 32 + 24) = *(const uint4*)(o + 24);
    if (seg == 3) {
        unsigned short t[16] = {0};
        t[0] = f2bf(dg);
        t[1] = f2bf(dl[r] * inv);
        t[2] = f2bf(1.0f);
        *(uint4*)(row + 256)     = *(const uint4*)(t);
        *(uint4*)(row + 256 + 8) = *(const uint4*)(t + 8);
    }
}

// ---- fused MLP+LN: 32x32x16 MFMA, swapped orientation, in-register h hand-off (unchanged).
__global__ __launch_bounds__(256, 2) void fused_mlp_ln(const unsigned short* __restrict__ featbf,
                                                       const unsigned short* __restrict__ W1Te,
                                                       const unsigned short* __restrict__ W2T,
                                                       const float* __restrict__ x,
                                                       const float* __restrict__ b2,
                                                       const float* __restrict__ gamma,
                                                       const float* __restrict__ beta,
                                                       float* __restrict__ out) {
    __shared__ __align__(16) unsigned char lds[34816 + 16384];
    unsigned char* B1 = lds;            // 64 w1cols x 272 k bf16, XOR-swizzled
    unsigned char* B2 = lds + 34816;    // 128 w2cols x 64 k slice bf16, XOR-swizzled

    int tid = threadIdx.x;
    int wave = tid >> 6, lane = tid & 63;
    int ln = lane & 31, hi = lane >> 5;
    int rowbase = blockIdx.x * 128 + wave * 32;
    int gr = rowbase + ln;
    int xorv = (ln & 7) << 4;

    bf16x8 ffr[17];
    if (gr < NN) {
        const unsigned char* fp = (const unsigned char*)featbf + (size_t)gr * KB + hi * 16;
#pragma unroll
        for (int ks = 0; ks < 17; ks++)
            ffr[ks] = *(const bf16x8*)(fp + ks * 32);
    } else {
#pragma unroll
        for (int ks = 0; ks < 17; ks++) ffr[ks] = (bf16x8)(__bf16)0.0f;
    }

    f32x16 acc2[4] = {};

    for (int ct = 0; ct < 8; ct++) {
        const unsigned short* s1 = W1Te + (size_t)(ct * 64) * KD;
        for (int i = tid; i < 2048; i += 256) {
            int c = i >> 5, slot = i & 31;
            uint4 v = *(const uint4*)(s1 + c * KD + slot * 8);
            *(uint4*)(B1 + ((c * KB + slot * 16) ^ ((c & 7) << 4))) = v;
        }
        if (tid < 128) {
            int c = tid >> 1, half = tid & 1;
            uint4 v = *(const uint4*)(s1 + c * KD + 256 + half * 8);
            *(uint4*)(B1 + ((c * KB + 512 + half * 16) ^ ((c & 7) << 4))) = v;
        }
        const unsigned short* s2 = W2T + ct * 64;
        for (int i = tid; i < 1024; i += 256) {
            int c = i >> 3, s = i & 7;
            uint4 v = *(const uint4*)(s2 + (size_t)c * 512 + s * 8);
            *(uint4*)(B2 + ((c * 128 + s * 16) ^ ((c & 7) << 4))) = v;
        }
        __syncthreads();

        f32x16 acc1[2] = {};
#pragma unroll
        for (int ks = 0; ks < 17; ks++) {
#pragma unroll
            for (int t = 0; t < 2; t++) {
                int col = t * 32 + ln;
                bf16x8 af = *(const bf16x8*)(B1 + ((col * KB + ks * 32 + hi * 16) ^ xorv));
                acc1[t] = __builtin_amdgcn_mfma_f32_32x32x16_bf16(af, ffr[ks], acc1[t], 0, 0, 0);
            }
        }

        unsigned int dw[2][4][2];
#pragma unroll
        for (int t = 0; t < 2; t++)
#pragma unroll
            for (int g = 0; g < 4; g++)
#pragma unroll
                for (int i = 0; i < 2; i++) {
                    float lo = fmaxf(acc1[t][g * 4 + 2 * i], 0.f);
                    float hf = fmaxf(acc1[t][g * 4 + 2 * i + 1], 0.f);
                    dw[t][g][i] = (unsigned int)f2bf(lo) | ((unsigned int)f2bf(hf) << 16);
                }

#pragma unroll
        for (int t = 0; t < 2; t++)
#pragma unroll
            for (int w = 0; w < 2; w++) {
                int ks2 = t * 2 + w;
                unsigned int sL0 = dw[t][2 * w][0],     sL1 = dw[t][2 * w][1];
                unsigned int sH0 = dw[t][2 * w + 1][0], sH1 = dw[t][2 * w + 1][1];
                unsigned int send0 = hi ? sL0 : sH0;
                unsigned int send1 = hi ? sL1 : sH1;
                unsigned int r0 = (unsigned int)__shfl_xor((int)send0, 32, 64);
                unsigned int r1 = (unsigned int)__shfl_xor((int)send1, 32, 64);
                uint4 fd;
                fd.x = hi ? r0 : sL0;
                fd.y = hi ? r1 : sL1;
                fd.z = hi ? sH0 : r0;
                fd.w = hi ? sH1 : r1;
                bf16x8 hfr = __builtin_bit_cast(bf16x8, fd);
#pragma unroll
                for (int at = 0; at < 4; at++) {
                    int col2 = at * 32 + ln;
                    bf16x8 a2 = *(const bf16x8*)(B2 + ((col2 * 128 + ks2 * 32 + hi * 16) ^ xorv));
                    acc2[at] = __builtin_amdgcn_mfma_f32_32x32x16_bf16(a2, hfr, acc2[at], 0, 0, 0);
                }
            }
        __syncthreads();
    }

    bool rok = (gr < NN);
    float sum = 0.f, sq = 0.f;
#pragma unroll
    for (int at = 0; at < 4; at++)
#pragma unroll
        for (int g = 0; g < 4; g++) {
            int c0 = at * 32 + g * 8 + hi * 4;
            float4 bq = *(const float4*)(b2 + c0);
            float4 xq = rok ? *(const float4*)(x + (size_t)gr * 128 + c0) : make_float4(0, 0, 0, 0);
            float vb[4] = { bq.x, bq.y, bq.z, bq.w };
            float vx[4] = { xq.x, xq.y, xq.z, xq.w };
#pragma unroll
            for (int m = 0; m < 4; m++) {
                float v = acc2[at][g * 4 + m] + vb[m] + vx[m];
                acc2[at][g * 4 + m] = v;
                sum += v;
                sq += v * v;
            }
        }
    sum += __shfl_xor(sum, 32, 64);
    sq  += __shfl_xor(sq, 32, 64);
    float mu = sum * (1.0f / 128.0f);
    float var = sq * (1.0f / 128.0f) - mu * mu;
    float rs = rsqrtf(var + LN_EPS);
    if (rok) {
        float* orow = out + (size_t)gr * 128;
#pragma unroll
        for (int at = 0; at < 4; at++)
#pragma unroll
            for (int g = 0; g < 4; g++) {
                int c0 = at * 32 + g * 8 + hi * 4;
                float4 gq = *(const float4*)(gamma + c0);
                float4 be = *(const float4*)(beta + c0);
                float4 o;
                o.x = (acc2[at][g * 4 + 0] - mu) * rs * gq.x + be.x;
                o.y = (acc2[at][g * 4 + 1] - mu) * rs * gq.y + be.y;
                o.z = (acc2[at][g * 4 + 2] - mu) * rs * gq.z + be.z;
                o.w = (acc2[at][g * 4 + 3] - mu) * rs * gq.w + be.w;
                *(float4*)(orow + c0) = o;
            }
    }
}

extern "C" void kernel_launch(void* const* d_in, const int* in_sizes, int n_in,
                              void* d_out, int out_size, void* d_ws, size_t ws_size,
                              hipStream_t stream) {
    const float* x       = (const float*)d_in[0];
    const float* W1      = (const float*)d_in[1];
    const float* b1      = (const float*)d_in[2];
    const float* W2      = (const float*)d_in[3];
    const float* b2      = (const float*)d_in[4];
    const float* gamma   = (const float*)d_in[5];
    const float* beta    = (const float*)d_in[6];
    const int*   ei      = (const int*)d_in[7];
    const float* edist   = (const float*)d_in[8];
    const float* degrees = (const float*)d_in[9];
    float* out = (float*)d_out;

    char* ws = (char*)d_ws;
    size_t off = 0;
    auto alloc = [&](size_t bytes) {
        void* p = ws + off;
        off = (off + bytes + 255) & ~(size_t)255;
        return p;
    };
    uint2* recs             = (uint2*)alloc((size_t)EE * 8);        // 5.12 MB
    int* bcnt               = (int*)alloc(NBK * 4);
    int* gbase              = (int*)alloc(NBK * 4);
    int* gcur               = (int*)alloc(NBK * 4);
    unsigned short* xbf     = (unsigned short*)alloc((size_t)NN * 128 * 2);
    unsigned short* featbf  = (unsigned short*)alloc((size_t)NN * KD * 2);
    unsigned short* W1Te    = (unsigned short*)alloc((size_t)512 * KD * 2);
    unsigned short* W2T     = (unsigned short*)alloc((size_t)128 * 512 * 2);

    cast_x<<<3125, 256, 0, stream>>>(x, xbf);
    prep_weights<<<640, 256, 0, stream>>>(W1, b1, W2, W1Te, W2T);
    hist_kernel<<<NBK, 128, 0, stream>>>(degrees, bcnt);
    scan_buckets<<<1, 256, 0, stream>>>(bcnt, gbase, gcur);
    bin_kernel<<<(EE + CH - 1) / CH, 256, 0, stream>>>(ei, edist, gcur, recs);
    aggbucket_kernel<<<NBK * 2, 256, 0, stream>>>(xbf, recs, gbase, bcnt, degrees, featbf);
    fused_mlp_ln<<<(NN + 127) / 128, 256, 0, stream>>>(featbf, W1Te, W2T, x, b2, gamma, beta, out);
}